// Round 15
// baseline (1153.538 us; speedup 1.0000x reference)
//
#include <hip/hip_runtime.h>
#include <math.h>

// Problem constants (fixed by the reference setup)
#define B_SZ   64
#define C_SZ   12
#define T_SZ   2048
#define K_SZ   2048
#define LMAX   11
#define CMAX   11     // C-1
#define PL_PAD 1024
#define A_PARAM 7.0f

#define NW     8      // waves per block in main kernel
#define BLOCK_MAIN (NW * 64)
#define R      8      // outputs per item

typedef _Float16 h2 __attribute__((ext_vector_type(2)));

// Scalar h2 ops on u32 payloads. Arrays stay 'unsigned' everywhere (rounds
// 8-13 lesson: unions / vector-typed ARRAYS / inline-asm => scratch spills).
__device__ __forceinline__ unsigned fma2u(unsigned w, unsigned v, unsigned acc) {
    const h2 r = __builtin_elementwise_fma(__builtin_bit_cast(h2, w),
                                           __builtin_bit_cast(h2, v),
                                           __builtin_bit_cast(h2, acc));
    return __builtin_bit_cast(unsigned, r);
}
__device__ __forceinline__ unsigned add2u(unsigned a, unsigned b) {
    const h2 r = __builtin_bit_cast(h2, a) + __builtin_bit_cast(h2, b);
    return __builtin_bit_cast(unsigned, r);
}
__device__ __forceinline__ float lo_f(unsigned u) {
    return (float)__builtin_bit_cast(_Float16, (unsigned short)(u & 0xFFFFu));
}
__device__ __forceinline__ float hi_f(unsigned u) {
    return (float)__builtin_bit_cast(_Float16, (unsigned short)(u >> 16));
}

// ---------------------------------------------------------------------------
// Transpose to fp16: xT[c][t][b] = fp16(x[b][c][t]). 3.15 MB -> per-XCD L2.
// Viewed as u32: xT2[c][t][bp] = {batch 2bp, batch 2bp+1}.
__global__ __launch_bounds__(256) void trh_kernel(const float* __restrict__ x,
                                                  unsigned short* __restrict__ xT) {
    const int c    = blockIdx.x;
    const int lane = threadIdx.x & 63;
    const int wid  = threadIdx.x >> 6;
    const int t0   = blockIdx.y * 128 + wid * 32;
    const float* xrow = x + ((size_t)lane * C_SZ + c) * T_SZ + t0;
    unsigned short* dst = xT + ((size_t)c * T_SZ + t0) * 64 + lane;
    #pragma unroll 8
    for (int i = 0; i < 32; ++i) {
        const _Float16 h = (_Float16)xrow[i];
        dst[i * 64] = __builtin_bit_cast(unsigned short, h);
    }
}

// ---------------------------------------------------------------------------
// Schedule: cost[k] ~ n*L*ceil(olen/128). Bitonic sort descending (LPT).
__global__ __launch_bounds__(1024) void sched_kernel(const float* __restrict__ w,
                                                     const int* __restrict__ olens,
                                                     unsigned* __restrict__ perm) {
    __shared__ unsigned key[K_SZ];
    const int tid = threadIdx.x;

    for (int k = tid; k < K_SZ; k += 1024) {
        const float* wk = w + (size_t)k * (CMAX * LMAX);
        int n = 0, L = 0;
        for (int e = 0; e < CMAX * LMAX; ++e) {
            if (wk[e] != 0.0f) {
                const int c = e / LMAX, l = e % LMAX;
                n = max(n, c + 1);
                L = max(L, l + 1);
            }
        }
        const unsigned cost = (unsigned)(n * L) * (unsigned)((olens[k] + 127) >> 7);
        key[k] = (cost << 11) | (unsigned)k;
    }
    __syncthreads();

    for (int ksz = 2; ksz <= K_SZ; ksz <<= 1) {
        for (int j = ksz >> 1; j > 0; j >>= 1) {
            for (int i = tid; i < K_SZ; i += 1024) {
                const int ixj = i ^ j;
                if (ixj > i) {
                    const unsigned a = key[i], b = key[ixj];
                    const bool sw = ((i & ksz) == 0) ? (a < b) : (a > b); // descending
                    if (sw) { key[i] = b; key[ixj] = a; }
                }
            }
            __syncthreads();
        }
    }
    for (int i = tid; i < K_SZ; i += 1024)
        perm[i] = key[i] & 0x7FFu;
}

// ---------------------------------------------------------------------------
// Channel-split batch-pack scheme with a 2-deep software pipeline across
// channel passes: issue pass p+1's 18 loads BEFORE pass p's 88 pk_fma block
// (double-buffered vpA/vpB), so the FMA block (~176cy) hides L2 latency.
#define LOADP(P, VP) do {                                                  \
    const int voff_ = sChOff[2 * (P) + h] + bp;                            \
    const unsigned* rp_ = rpbase;                                          \
    _Pragma("unroll")                                                      \
    for (int i_ = 0; i_ < NV; ++i_) { VP[i_] = rp_[voff_]; rp_ += d32; }   \
} while (0)

#define FMAP(P, VP) do {                                                   \
    const unsigned* wrow_ = &sWs[2 * (P) + h][0];                          \
    _Pragma("unroll")                                                      \
    for (int l_ = 0; l_ < LC; ++l_) {                                      \
        const unsigned wl_ = wrow_[l_];                                    \
        _Pragma("unroll")                                                  \
        for (int r_ = 0; r_ < R; ++r_)                                     \
            y[r_] = fma2u(wl_, VP[l_ + r_], y[r_]);                        \
    }                                                                      \
} while (0)

template<int LC>
__device__ __forceinline__ void conv_all(
    const unsigned* __restrict__ xT2,
    const int*      __restrict__ sChOff,       // [12] channel row elem offsets
    const unsigned  (* __restrict__ sWs)[LMAX],// [12][LMAX] splat {w,w} (row 11 = 0)
    int npass, int d, int offr, int olen, unsigned yinit,
    int bp, int h, int wid,
    float& psum_lo, float& psum_hi, float& pmax_lo, float& pmax_hi)
{
    constexpr int NV = R + LC - 1;            // taps spanned by one item

    const int nj   = (olen + d - 1) / d;      // outputs per residue chain
    const int njb  = (nj + R - 1) / R;        // items per chain
    const int S    = (d >= 64) ? 1 : ((64 + d - 1) / d);
    const int len  = (njb + S - 1) / S;
    const int nunits = d * S;
    const int d32  = d * 32;

    for (int u = wid; u < nunits; u += NW) {
        int q, seg;
        if (S == 1) { q = u; seg = 0; }
        else        { q = u % d; seg = u / d; }   // wave-uniform div
        const int jb0 = seg * len;
        const int jb1 = min(njb, jb0 + len);

        for (int jb = jb0; jb < jb1; ++jb) {
            const int tq = q + jb * (R * d);      // first output t of this item
            if (tq >= olen) break;
            const int tpos0 = tq + offr;          // real x coord of tap 0

            unsigned y[R];
            #pragma unroll
            for (int r = 0; r < R; ++r) y[r] = yinit;

            const bool fast = (tpos0 >= 0) && (tpos0 + (NV - 1) * d < T_SZ);

            if (fast) {
                const unsigned* rpbase =
                    xT2 + (size_t)__builtin_amdgcn_readfirstlane(tpos0) * 32;
                unsigned vpA[NV], vpB[NV];
                LOADP(0, vpA);
                int p = 0;
                for (;;) {
                    if (p + 1 < npass) LOADP(p + 1, vpB);   // prefetch (hidden)
                    FMAP(p, vpA);
                    if (++p >= npass) break;
                    if (p + 1 < npass) LOADP(p + 1, vpA);
                    FMAP(p, vpB);
                    if (++p >= npass) break;
                }
            } else {
                for (int p = 0; p < npass; ++p) {
                    const int voff = sChOff[2 * p + h] + bp;
                    unsigned vp[NV];
                    #pragma unroll
                    for (int i = 0; i < NV; ++i) {
                        const int tp  = tpos0 + i * d;         // wave-uniform
                        const int tpc = min(max(tp, 0), T_SZ - 1);
                        const unsigned* rp =
                            xT2 + (size_t)__builtin_amdgcn_readfirstlane(tpc) * 32;
                        const unsigned v = rp[voff];
                        vp[i] = ((unsigned)tp < (unsigned)T_SZ) ? v : 0u;
                    }
                    const unsigned* wrow = &sWs[2 * p + h][0];
                    #pragma unroll
                    for (int l = 0; l < LC; ++l) {
                        const unsigned wl = wrow[l];
                        #pragma unroll
                        for (int r = 0; r < R; ++r)
                            y[r] = fma2u(wl, vp[l + r], y[r]);
                    }
                }
            }

            // Combine channel halves, then sigmoid/max on h==0 lanes only.
            #pragma unroll
            for (int r = 0; r < R; ++r) {
                const unsigned yo = (unsigned)__shfl_xor((int)y[r], 32, 64);
                const int tl = tq + r * d;                    // uniform
                if (h == 0 && tl < olen) {
                    const unsigned yc = add2u(y[r], yo);
                    const float ylo = lo_f(yc);
                    const float yhi = hi_f(yc);
                    psum_lo += 1.0f / (1.0f + __expf(3.0f - A_PARAM * ylo));
                    psum_hi += 1.0f / (1.0f + __expf(3.0f - A_PARAM * yhi));
                    pmax_lo  = fmaxf(pmax_lo, ylo);
                    pmax_hi  = fmaxf(pmax_hi, yhi);
                }
            }
        }
    }
}

__global__ __launch_bounds__(BLOCK_MAIN, 8) void rocket_tr(
    const unsigned* __restrict__ xT2,        // (C, T, 32) fp16 batch pairs
    const unsigned* __restrict__ perm,       // heavy-first block -> k map
    const float* __restrict__ weights,       // (K, CMAX, LMAX)
    const float* __restrict__ biases,
    const int*   __restrict__ ch_idx,        // (K, CMAX)
    const int*   __restrict__ dils,
    const int*   __restrict__ offs,
    const int*   __restrict__ olens,
    float*       __restrict__ out)           // (B, 2K)
{
    __shared__ float    sW[CMAX][LMAX];
    __shared__ unsigned sWs[12][LMAX];       // splat {w,w}; row 11 zeroed
    __shared__ int      sChOff[12];          // channel row element offsets
    __shared__ int      sMeta[2];
    __shared__ float    sPlo[NW][64];
    __shared__ float    sPhi[NW][64];
    __shared__ float    sMlo[NW][64];
    __shared__ float    sMhi[NW][64];

    const int k   = (int)perm[blockIdx.x];
    const int tid = threadIdx.x;

    if (tid < CMAX * LMAX)
        sW[tid / LMAX][tid % LMAX] = weights[(size_t)k * (CMAX * LMAX) + tid];
    if (tid < 12)
        sChOff[tid] = (tid < CMAX) ? ch_idx[(size_t)k * CMAX + tid] * (T_SZ * 32) : 0;
    __syncthreads();

    if (tid < 12 * LMAX) {
        const int c = tid / LMAX, l = tid % LMAX;
        const float wf = (c < CMAX) ? sW[c][l] : 0.0f;
        const unsigned wh =
            (unsigned)__builtin_bit_cast(unsigned short, (_Float16)wf);
        sWs[c][l] = wh | (wh << 16);
    }
    if (tid == 0) {
        // Effective channel/tap counts (zero-padded rows/taps contribute 0).
        int n = 0, L = 0;
        for (int c = 0; c < CMAX; ++c) {
            bool nz = false;
            for (int l = 0; l < LMAX; ++l) {
                if (sW[c][l] != 0.0f) { nz = true; if (l + 1 > L) L = l + 1; }
            }
            if (nz) n = c + 1;
        }
        sMeta[0] = n; sMeta[1] = L;
    }
    __syncthreads();

    const int   n     = sMeta[0];
    const int   L     = sMeta[1];
    const int   npass = (n + 1) >> 1;
    const int   d     = dils[k];
    const int   offr  = offs[k] - PL_PAD;  // real x coord offset (may be <0)
    const int   olen  = olens[k];
    const float bias  = biases[k];
    const int   lane  = tid & 63;
    const int   bp    = lane & 31;
    const int   h     = lane >> 5;
    const int   wid   = __builtin_amdgcn_readfirstlane(tid >> 6);

    const unsigned bh =
        (unsigned)__builtin_bit_cast(unsigned short, (_Float16)bias);
    const unsigned yinit = h ? 0u : (bh | (bh << 16));   // bias once (h=0 only)

    float psum_lo = 0.0f, psum_hi = 0.0f;
    float pmax_lo = -INFINITY, pmax_hi = -INFINITY;

    if (L <= 7)
        conv_all<7 >(xT2, sChOff, sWs, npass, d, offr, olen, yinit, bp, h, wid,
                     psum_lo, psum_hi, pmax_lo, pmax_hi);
    else if (L <= 9)
        conv_all<9 >(xT2, sChOff, sWs, npass, d, offr, olen, yinit, bp, h, wid,
                     psum_lo, psum_hi, pmax_lo, pmax_hi);
    else
        conv_all<11>(xT2, sChOff, sWs, npass, d, offr, olen, yinit, bp, h, wid,
                     psum_lo, psum_hi, pmax_lo, pmax_hi);

    sPlo[wid][lane] = psum_lo;    // h=1 lanes hold 0 / -inf (harmless)
    sPhi[wid][lane] = psum_hi;
    sMlo[wid][lane] = pmax_lo;
    sMhi[wid][lane] = pmax_hi;
    __syncthreads();

    if (tid < 64) {
        const int b   = tid;           // batch
        const int bp2 = b >> 1;
        const int odd = b & 1;         // 0 -> lo half of pack, 1 -> hi
        float s = 0.0f, m = -INFINITY;
        #pragma unroll
        for (int w = 0; w < NW; ++w) {
            const float s0 = odd ? sPhi[w][bp2]      : sPlo[w][bp2];
            const float s1 = odd ? sPhi[w][32 + bp2] : sPlo[w][32 + bp2];
            const float m0 = odd ? sMhi[w][bp2]      : sMlo[w][bp2];
            const float m1 = odd ? sMhi[w][32 + bp2] : sMlo[w][32 + bp2];
            s += s0 + s1;
            m  = fmaxf(m, fmaxf(m0, m1));
        }
        const float inv_olen = 1.0f / (float)olen;
        out[(size_t)b * (2 * K_SZ) + 2 * k]     = s * inv_olen;
        out[(size_t)b * (2 * K_SZ) + 2 * k + 1] = m;
    }
}

// ---------------------------------------------------------------------------
// Fallback (ws too small): simple checked-gather kernel, known correct.
__global__ __launch_bounds__(256) void rocket_fallback(
    const float* __restrict__ x,
    const float* __restrict__ weights,
    const float* __restrict__ biases,
    const int*   __restrict__ ch_idx,
    const int*   __restrict__ dils,
    const int*   __restrict__ offs,
    const int*   __restrict__ olens,
    float*       __restrict__ out)
{
    __shared__ float sW[CMAX][LMAX];
    __shared__ int   sCh[CMAX];
    __shared__ float sRed[2][4];

    const int k   = blockIdx.x;
    const int tid = threadIdx.x;

    if (tid < CMAX * LMAX)
        sW[tid / LMAX][tid % LMAX] = weights[(size_t)k * (CMAX * LMAX) + tid];
    if (tid < CMAX)
        sCh[tid] = ch_idx[(size_t)k * CMAX + tid];
    __syncthreads();

    const int   d    = dils[k];
    const int   off  = offs[k] - PL_PAD;
    const int   olen = olens[k];
    const float bias = biases[k];
    const int   lane = tid & 63;
    const int   wid  = tid >> 6;

    for (int b = blockIdx.y; b < B_SZ; b += gridDim.y) {
        float psum = 0.0f, pmax = -INFINITY;
        for (int t = tid; t < T_SZ; t += 256) {
            float y = bias;
            for (int c = 0; c < CMAX; ++c) {
                const float* xb = x + ((size_t)b * C_SZ + sCh[c]) * T_SZ;
                int pos = off + t;
                for (int l = 0; l < LMAX; ++l) {
                    const float xv = ((unsigned)pos < (unsigned)T_SZ) ? xb[pos] : 0.0f;
                    y = fmaf(sW[c][l], xv, y);
                    pos += d;
                }
            }
            if (t < olen) {
                psum += 1.0f / (1.0f + __expf(3.0f - A_PARAM * y));
                pmax = fmaxf(pmax, y);
            }
        }
        for (int o = 32; o > 0; o >>= 1) {
            psum += __shfl_down(psum, o, 64);
            pmax  = fmaxf(pmax, __shfl_down(pmax, o, 64));
        }
        if (lane == 0) { sRed[0][wid] = psum; sRed[1][wid] = pmax; }
        __syncthreads();
        if (tid == 0) {
            const float s = sRed[0][0] + sRed[0][1] + sRed[0][2] + sRed[0][3];
            const float m = fmaxf(fmaxf(sRed[1][0], sRed[1][1]),
                                  fmaxf(sRed[1][2], sRed[1][3]));
            out[(size_t)b * (2 * K_SZ) + 2 * k]     = s / (float)olen;
            out[(size_t)b * (2 * K_SZ) + 2 * k + 1] = m;
        }
        __syncthreads();
    }
}

// ---------------------------------------------------------------------------
extern "C" void kernel_launch(void* const* d_in, const int* in_sizes, int n_in,
                              void* d_out, int out_size, void* d_ws, size_t ws_size,
                              hipStream_t stream) {
    const float* x       = (const float*)d_in[0];
    const float* weights = (const float*)d_in[1];
    const float* biases  = (const float*)d_in[2];
    const int*   ch_idx  = (const int*)  d_in[3];
    const int*   dils    = (const int*)  d_in[4];
    const int*   offs    = (const int*)  d_in[5];
    const int*   olens   = (const int*)  d_in[6];
    float*       out     = (float*)d_out;

    const size_t xt_bytes = (size_t)C_SZ * T_SZ * 64 * sizeof(unsigned short); // 3.15 MB
    const size_t need     = xt_bytes + K_SZ * sizeof(unsigned);

    if (ws_size >= need) {
        unsigned short* xT = (unsigned short*)d_ws;
        unsigned* perm     = (unsigned*)((char*)d_ws + xt_bytes);
        dim3 tgrid(C_SZ, T_SZ / 128);
        trh_kernel<<<tgrid, 256, 0, stream>>>(x, xT);
        sched_kernel<<<1, 1024, 0, stream>>>(weights, olens, perm);
        rocket_tr<<<K_SZ, BLOCK_MAIN, 0, stream>>>((const unsigned*)xT, perm,
                                                   weights, biases, ch_idx,
                                                   dils, offs, olens, out);
    } else {
        dim3 grid(K_SZ, 16);
        rocket_fallback<<<grid, 256, 0, stream>>>(x, weights, biases, ch_idx,
                                                  dils, offs, olens, out);
    }
}

// Round 16
// 838.027 us; speedup vs baseline: 1.3765x; 1.3765x over previous
//
#include <hip/hip_runtime.h>
#include <math.h>

// Problem constants (fixed by the reference setup)
#define B_SZ   64
#define C_SZ   12
#define T_SZ   2048
#define K_SZ   2048
#define LMAX   11
#define CMAX   11     // C-1
#define PL_PAD 1024
#define A_PARAM 7.0f

#define NW     8      // waves per block in main kernel
#define BLOCK_MAIN (NW * 64)
#define R      8      // outputs per item

typedef _Float16 h2 __attribute__((ext_vector_type(2)));

// Scalar h2 ops on u32 payloads. Arrays stay 'unsigned' everywhere (rounds
// 8-13 lesson: unions / vector-typed ARRAYS / inline-asm => scratch spills).
__device__ __forceinline__ unsigned fma2u(unsigned w, unsigned v, unsigned acc) {
    const h2 r = __builtin_elementwise_fma(__builtin_bit_cast(h2, w),
                                           __builtin_bit_cast(h2, v),
                                           __builtin_bit_cast(h2, acc));
    return __builtin_bit_cast(unsigned, r);
}
__device__ __forceinline__ unsigned add2u(unsigned a, unsigned b) {
    const h2 r = __builtin_bit_cast(h2, a) + __builtin_bit_cast(h2, b);
    return __builtin_bit_cast(unsigned, r);
}
__device__ __forceinline__ float lo_f(unsigned u) {
    return (float)__builtin_bit_cast(_Float16, (unsigned short)(u & 0xFFFFu));
}
__device__ __forceinline__ float hi_f(unsigned u) {
    return (float)__builtin_bit_cast(_Float16, (unsigned short)(u >> 16));
}

// ---------------------------------------------------------------------------
// Transpose to fp16: xT[c][t][b] = fp16(x[b][c][t]). 3.15 MB -> per-XCD L2.
// Viewed as u32: xT2[c][t][bp] = {batch 2bp, batch 2bp+1}.
__global__ __launch_bounds__(256) void trh_kernel(const float* __restrict__ x,
                                                  unsigned short* __restrict__ xT) {
    const int c    = blockIdx.x;
    const int lane = threadIdx.x & 63;
    const int wid  = threadIdx.x >> 6;
    const int t0   = blockIdx.y * 128 + wid * 32;
    const float* xrow = x + ((size_t)lane * C_SZ + c) * T_SZ + t0;
    unsigned short* dst = xT + ((size_t)c * T_SZ + t0) * 64 + lane;
    #pragma unroll 8
    for (int i = 0; i < 32; ++i) {
        const _Float16 h = (_Float16)xrow[i];
        dst[i * 64] = __builtin_bit_cast(unsigned short, h);
    }
}

// ---------------------------------------------------------------------------
// Schedule: cost[k] ~ n*L*ceil(olen/128). Bitonic sort descending (LPT).
__global__ __launch_bounds__(1024) void sched_kernel(const float* __restrict__ w,
                                                     const int* __restrict__ olens,
                                                     unsigned* __restrict__ perm) {
    __shared__ unsigned key[K_SZ];
    const int tid = threadIdx.x;

    for (int k = tid; k < K_SZ; k += 1024) {
        const float* wk = w + (size_t)k * (CMAX * LMAX);
        int n = 0, L = 0;
        for (int e = 0; e < CMAX * LMAX; ++e) {
            if (wk[e] != 0.0f) {
                const int c = e / LMAX, l = e % LMAX;
                n = max(n, c + 1);
                L = max(L, l + 1);
            }
        }
        const unsigned cost = (unsigned)(n * L) * (unsigned)((olens[k] + 127) >> 7);
        key[k] = (cost << 11) | (unsigned)k;
    }
    __syncthreads();

    for (int ksz = 2; ksz <= K_SZ; ksz <<= 1) {
        for (int j = ksz >> 1; j > 0; j >>= 1) {
            for (int i = tid; i < K_SZ; i += 1024) {
                const int ixj = i ^ j;
                if (ixj > i) {
                    const unsigned a = key[i], b = key[ixj];
                    const bool sw = ((i & ksz) == 0) ? (a < b) : (a > b); // descending
                    if (sw) { key[i] = b; key[ixj] = a; }
                }
            }
            __syncthreads();
        }
    }
    for (int i = tid; i < K_SZ; i += 1024)
        perm[i] = key[i] & 0x7FFu;
}

// ---------------------------------------------------------------------------
// Channel-split batch-pack scheme with a 2-deep software pipeline across
// channel passes: issue pass p+1's 18 loads BEFORE pass p's 88 pk_fma block
// (double-buffered vpA/vpB), so the FMA block (~176cy) hides L2 latency.
// Needs ~54 live VGPRs -> requires the (BLOCK,4) bounds (64-reg budget).
#define LOADP(P, VP) do {                                                  \
    const int voff_ = sChOff[2 * (P) + h] + bp;                            \
    const unsigned* rp_ = rpbase;                                          \
    _Pragma("unroll")                                                      \
    for (int i_ = 0; i_ < NV; ++i_) { VP[i_] = rp_[voff_]; rp_ += d32; }   \
} while (0)

#define FMAP(P, VP) do {                                                   \
    const unsigned* wrow_ = &sWs[2 * (P) + h][0];                          \
    _Pragma("unroll")                                                      \
    for (int l_ = 0; l_ < LC; ++l_) {                                      \
        const unsigned wl_ = wrow_[l_];                                    \
        _Pragma("unroll")                                                  \
        for (int r_ = 0; r_ < R; ++r_)                                     \
            y[r_] = fma2u(wl_, VP[l_ + r_], y[r_]);                        \
    }                                                                      \
} while (0)

template<int LC>
__device__ __forceinline__ void conv_all(
    const unsigned* __restrict__ xT2,
    const int*      __restrict__ sChOff,       // [12] channel row elem offsets
    const unsigned  (* __restrict__ sWs)[LMAX],// [12][LMAX] splat {w,w} (row 11 = 0)
    int npass, int d, int offr, int olen, unsigned yinit,
    int bp, int h, int wid,
    float& psum_lo, float& psum_hi, float& pmax_lo, float& pmax_hi)
{
    constexpr int NV = R + LC - 1;            // taps spanned by one item

    const int nj   = (olen + d - 1) / d;      // outputs per residue chain
    const int njb  = (nj + R - 1) / R;        // items per chain
    const int S    = (d >= 64) ? 1 : ((64 + d - 1) / d);
    const int len  = (njb + S - 1) / S;
    const int nunits = d * S;
    const int d32  = d * 32;

    for (int u = wid; u < nunits; u += NW) {
        int q, seg;
        if (S == 1) { q = u; seg = 0; }
        else        { q = u % d; seg = u / d; }   // wave-uniform div
        const int jb0 = seg * len;
        const int jb1 = min(njb, jb0 + len);

        for (int jb = jb0; jb < jb1; ++jb) {
            const int tq = q + jb * (R * d);      // first output t of this item
            if (tq >= olen) break;
            const int tpos0 = tq + offr;          // real x coord of tap 0

            unsigned y[R];
            #pragma unroll
            for (int r = 0; r < R; ++r) y[r] = yinit;

            const bool fast = (tpos0 >= 0) && (tpos0 + (NV - 1) * d < T_SZ);

            if (fast) {
                const unsigned* rpbase =
                    xT2 + (size_t)__builtin_amdgcn_readfirstlane(tpos0) * 32;
                unsigned vpA[NV], vpB[NV];
                LOADP(0, vpA);
                int p = 0;
                for (;;) {
                    if (p + 1 < npass) LOADP(p + 1, vpB);   // prefetch (hidden)
                    FMAP(p, vpA);
                    if (++p >= npass) break;
                    if (p + 1 < npass) LOADP(p + 1, vpA);
                    FMAP(p, vpB);
                    if (++p >= npass) break;
                }
            } else {
                for (int p = 0; p < npass; ++p) {
                    const int voff = sChOff[2 * p + h] + bp;
                    unsigned vp[NV];
                    #pragma unroll
                    for (int i = 0; i < NV; ++i) {
                        const int tp  = tpos0 + i * d;         // wave-uniform
                        const int tpc = min(max(tp, 0), T_SZ - 1);
                        const unsigned* rp =
                            xT2 + (size_t)__builtin_amdgcn_readfirstlane(tpc) * 32;
                        const unsigned v = rp[voff];
                        vp[i] = ((unsigned)tp < (unsigned)T_SZ) ? v : 0u;
                    }
                    const unsigned* wrow = &sWs[2 * p + h][0];
                    #pragma unroll
                    for (int l = 0; l < LC; ++l) {
                        const unsigned wl = wrow[l];
                        #pragma unroll
                        for (int r = 0; r < R; ++r)
                            y[r] = fma2u(wl, vp[l + r], y[r]);
                    }
                }
            }

            // Combine channel halves, then sigmoid/max on h==0 lanes only.
            #pragma unroll
            for (int r = 0; r < R; ++r) {
                const unsigned yo = (unsigned)__shfl_xor((int)y[r], 32, 64);
                const int tl = tq + r * d;                    // uniform
                if (h == 0 && tl < olen) {
                    const unsigned yc = add2u(y[r], yo);
                    const float ylo = lo_f(yc);
                    const float yhi = hi_f(yc);
                    psum_lo += 1.0f / (1.0f + __expf(3.0f - A_PARAM * ylo));
                    psum_hi += 1.0f / (1.0f + __expf(3.0f - A_PARAM * yhi));
                    pmax_lo  = fmaxf(pmax_lo, ylo);
                    pmax_hi  = fmaxf(pmax_hi, yhi);
                }
            }
        }
    }
}

// NOTE: 2nd launch_bounds arg behaves as MIN BLOCKS PER CU on this toolchain
// (empirical: (512,8)->32 VGPR, (512,6)->40, none->68). (512,4) = 4 blk x 8
// waves = 32 waves/CU = SAME max occupancy as (512,8), but 64-VGPR budget.
__global__ __launch_bounds__(BLOCK_MAIN, 4) void rocket_tr(
    const unsigned* __restrict__ xT2,        // (C, T, 32) fp16 batch pairs
    const unsigned* __restrict__ perm,       // heavy-first block -> k map
    const float* __restrict__ weights,       // (K, CMAX, LMAX)
    const float* __restrict__ biases,
    const int*   __restrict__ ch_idx,        // (K, CMAX)
    const int*   __restrict__ dils,
    const int*   __restrict__ offs,
    const int*   __restrict__ olens,
    float*       __restrict__ out)           // (B, 2K)
{
    __shared__ float    sW[CMAX][LMAX];
    __shared__ unsigned sWs[12][LMAX];       // splat {w,w}; row 11 zeroed
    __shared__ int      sChOff[12];          // channel row element offsets
    __shared__ int      sMeta[2];
    __shared__ float    sPlo[NW][64];
    __shared__ float    sPhi[NW][64];
    __shared__ float    sMlo[NW][64];
    __shared__ float    sMhi[NW][64];

    const int k   = (int)perm[blockIdx.x];
    const int tid = threadIdx.x;

    if (tid < CMAX * LMAX)
        sW[tid / LMAX][tid % LMAX] = weights[(size_t)k * (CMAX * LMAX) + tid];
    if (tid < 12)
        sChOff[tid] = (tid < CMAX) ? ch_idx[(size_t)k * CMAX + tid] * (T_SZ * 32) : 0;
    __syncthreads();

    if (tid < 12 * LMAX) {
        const int c = tid / LMAX, l = tid % LMAX;
        const float wf = (c < CMAX) ? sW[c][l] : 0.0f;
        const unsigned wh =
            (unsigned)__builtin_bit_cast(unsigned short, (_Float16)wf);
        sWs[c][l] = wh | (wh << 16);
    }
    if (tid == 0) {
        // Effective channel/tap counts (zero-padded rows/taps contribute 0).
        int n = 0, L = 0;
        for (int c = 0; c < CMAX; ++c) {
            bool nz = false;
            for (int l = 0; l < LMAX; ++l) {
                if (sW[c][l] != 0.0f) { nz = true; if (l + 1 > L) L = l + 1; }
            }
            if (nz) n = c + 1;
        }
        sMeta[0] = n; sMeta[1] = L;
    }
    __syncthreads();

    const int   n     = sMeta[0];
    const int   L     = sMeta[1];
    const int   npass = (n + 1) >> 1;
    const int   d     = dils[k];
    const int   offr  = offs[k] - PL_PAD;  // real x coord offset (may be <0)
    const int   olen  = olens[k];
    const float bias  = biases[k];
    const int   lane  = tid & 63;
    const int   bp    = lane & 31;
    const int   h     = lane >> 5;
    const int   wid   = __builtin_amdgcn_readfirstlane(tid >> 6);

    const unsigned bh =
        (unsigned)__builtin_bit_cast(unsigned short, (_Float16)bias);
    const unsigned yinit = h ? 0u : (bh | (bh << 16));   // bias once (h=0 only)

    float psum_lo = 0.0f, psum_hi = 0.0f;
    float pmax_lo = -INFINITY, pmax_hi = -INFINITY;

    if (L <= 7)
        conv_all<7 >(xT2, sChOff, sWs, npass, d, offr, olen, yinit, bp, h, wid,
                     psum_lo, psum_hi, pmax_lo, pmax_hi);
    else if (L <= 9)
        conv_all<9 >(xT2, sChOff, sWs, npass, d, offr, olen, yinit, bp, h, wid,
                     psum_lo, psum_hi, pmax_lo, pmax_hi);
    else
        conv_all<11>(xT2, sChOff, sWs, npass, d, offr, olen, yinit, bp, h, wid,
                     psum_lo, psum_hi, pmax_lo, pmax_hi);

    sPlo[wid][lane] = psum_lo;    // h=1 lanes hold 0 / -inf (harmless)
    sPhi[wid][lane] = psum_hi;
    sMlo[wid][lane] = pmax_lo;
    sMhi[wid][lane] = pmax_hi;
    __syncthreads();

    if (tid < 64) {
        const int b   = tid;           // batch
        const int bp2 = b >> 1;
        const int odd = b & 1;         // 0 -> lo half of pack, 1 -> hi
        float s = 0.0f, m = -INFINITY;
        #pragma unroll
        for (int w = 0; w < NW; ++w) {
            const float s0 = odd ? sPhi[w][bp2]      : sPlo[w][bp2];
            const float s1 = odd ? sPhi[w][32 + bp2] : sPlo[w][32 + bp2];
            const float m0 = odd ? sMhi[w][bp2]      : sMlo[w][bp2];
            const float m1 = odd ? sMhi[w][32 + bp2] : sMlo[w][32 + bp2];
            s += s0 + s1;
            m  = fmaxf(m, fmaxf(m0, m1));
        }
        const float inv_olen = 1.0f / (float)olen;
        out[(size_t)b * (2 * K_SZ) + 2 * k]     = s * inv_olen;
        out[(size_t)b * (2 * K_SZ) + 2 * k + 1] = m;
    }
}

// ---------------------------------------------------------------------------
// Fallback (ws too small): simple checked-gather kernel, known correct.
__global__ __launch_bounds__(256) void rocket_fallback(
    const float* __restrict__ x,
    const float* __restrict__ weights,
    const float* __restrict__ biases,
    const int*   __restrict__ ch_idx,
    const int*   __restrict__ dils,
    const int*   __restrict__ offs,
    const int*   __restrict__ olens,
    float*       __restrict__ out)
{
    __shared__ float sW[CMAX][LMAX];
    __shared__ int   sCh[CMAX];
    __shared__ float sRed[2][4];

    const int k   = blockIdx.x;
    const int tid = threadIdx.x;

    if (tid < CMAX * LMAX)
        sW[tid / LMAX][tid % LMAX] = weights[(size_t)k * (CMAX * LMAX) + tid];
    if (tid < CMAX)
        sCh[tid] = ch_idx[(size_t)k * CMAX + tid];
    __syncthreads();

    const int   d    = dils[k];
    const int   off  = offs[k] - PL_PAD;
    const int   olen = olens[k];
    const float bias = biases[k];
    const int   lane = tid & 63;
    const int   wid  = tid >> 6;

    for (int b = blockIdx.y; b < B_SZ; b += gridDim.y) {
        float psum = 0.0f, pmax = -INFINITY;
        for (int t = tid; t < T_SZ; t += 256) {
            float y = bias;
            for (int c = 0; c < CMAX; ++c) {
                const float* xb = x + ((size_t)b * C_SZ + sCh[c]) * T_SZ;
                int pos = off + t;
                for (int l = 0; l < LMAX; ++l) {
                    const float xv = ((unsigned)pos < (unsigned)T_SZ) ? xb[pos] : 0.0f;
                    y = fmaf(sW[c][l], xv, y);
                    pos += d;
                }
            }
            if (t < olen) {
                psum += 1.0f / (1.0f + __expf(3.0f - A_PARAM * y));
                pmax = fmaxf(pmax, y);
            }
        }
        for (int o = 32; o > 0; o >>= 1) {
            psum += __shfl_down(psum, o, 64);
            pmax  = fmaxf(pmax, __shfl_down(pmax, o, 64));
        }
        if (lane == 0) { sRed[0][wid] = psum; sRed[1][wid] = pmax; }
        __syncthreads();
        if (tid == 0) {
            const float s = sRed[0][0] + sRed[0][1] + sRed[0][2] + sRed[0][3];
            const float m = fmaxf(fmaxf(sRed[1][0], sRed[1][1]),
                                  fmaxf(sRed[1][2], sRed[1][3]));
            out[(size_t)b * (2 * K_SZ) + 2 * k]     = s / (float)olen;
            out[(size_t)b * (2 * K_SZ) + 2 * k + 1] = m;
        }
        __syncthreads();
    }
}

// ---------------------------------------------------------------------------
extern "C" void kernel_launch(void* const* d_in, const int* in_sizes, int n_in,
                              void* d_out, int out_size, void* d_ws, size_t ws_size,
                              hipStream_t stream) {
    const float* x       = (const float*)d_in[0];
    const float* weights = (const float*)d_in[1];
    const float* biases  = (const float*)d_in[2];
    const int*   ch_idx  = (const int*)  d_in[3];
    const int*   dils    = (const int*)  d_in[4];
    const int*   offs    = (const int*)  d_in[5];
    const int*   olens   = (const int*)  d_in[6];
    float*       out     = (float*)d_out;

    const size_t xt_bytes = (size_t)C_SZ * T_SZ * 64 * sizeof(unsigned short); // 3.15 MB
    const size_t need     = xt_bytes + K_SZ * sizeof(unsigned);

    if (ws_size >= need) {
        unsigned short* xT = (unsigned short*)d_ws;
        unsigned* perm     = (unsigned*)((char*)d_ws + xt_bytes);
        dim3 tgrid(C_SZ, T_SZ / 128);
        trh_kernel<<<tgrid, 256, 0, stream>>>(x, xT);
        sched_kernel<<<1, 1024, 0, stream>>>(weights, olens, perm);
        rocket_tr<<<K_SZ, BLOCK_MAIN, 0, stream>>>((const unsigned*)xT, perm,
                                                   weights, biases, ch_idx,
                                                   dils, offs, olens, out);
    } else {
        dim3 grid(K_SZ, 16);
        rocket_fallback<<<grid, 256, 0, stream>>>(x, weights, biases, ch_idx,
                                                  dils, offs, olens, out);
    }
}

// Round 17
// 678.024 us; speedup vs baseline: 1.7013x; 1.2360x over previous
//
#include <hip/hip_runtime.h>
#include <math.h>

// Problem constants (fixed by the reference setup)
#define B_SZ   64
#define C_SZ   12
#define T_SZ   2048
#define K_SZ   2048
#define LMAX   11
#define CMAX   11     // C-1
#define NPAIR  6      // channel pairs: ceil(12/2), padded with zero-weight
#define PL_PAD 1024
#define A_PARAM 7.0f

#define NW     8      // waves per block in main kernel
#define BLOCK_MAIN (NW * 64)
#define R      8      // outputs per thread item (dilation-strided register tile)
#define SPL    4      // chain-splits per kernel (8192 blocks -> better packing)

typedef _Float16 h2 __attribute__((ext_vector_type(2)));

// Pure register bitcast — NO union (unions defeat SROA -> scratch arrays).
__device__ __forceinline__ float fdot2f(unsigned w, unsigned v, float acc) {
    return __builtin_amdgcn_fdot2(__builtin_bit_cast(h2, w),
                                  __builtin_bit_cast(h2, v), acc, false);
}

// ---------------------------------------------------------------------------
// Transpose to fp16: xT[c][t][b] = fp16(x[b][c][t]). 3.15 MB -> per-XCD L2.
__global__ __launch_bounds__(256) void trh_kernel(const float* __restrict__ x,
                                                  unsigned short* __restrict__ xT) {
    const int c    = blockIdx.x;
    const int lane = threadIdx.x & 63;
    const int wid  = threadIdx.x >> 6;
    const int t0   = blockIdx.y * 128 + wid * 32;
    const float* xrow = x + ((size_t)lane * C_SZ + c) * T_SZ + t0;
    unsigned short* dst = xT + ((size_t)c * T_SZ + t0) * 64 + lane;
    #pragma unroll 8
    for (int i = 0; i < 32; ++i) {
        const _Float16 h = (_Float16)xrow[i];
        dst[i * 64] = __builtin_bit_cast(unsigned short, h);
    }
}

// ---------------------------------------------------------------------------
// Schedule: cost[k] ~ n*L*ceil(olen/128). Bitonic sort descending (LPT).
__global__ __launch_bounds__(1024) void sched_kernel(const float* __restrict__ w,
                                                     const int* __restrict__ olens,
                                                     unsigned* __restrict__ perm) {
    __shared__ unsigned key[K_SZ];
    const int tid = threadIdx.x;

    for (int k = tid; k < K_SZ; k += 1024) {
        const float* wk = w + (size_t)k * (CMAX * LMAX);
        int n = 0, L = 0;
        for (int e = 0; e < CMAX * LMAX; ++e) {
            if (wk[e] != 0.0f) {
                const int c = e / LMAX, l = e % LMAX;
                n = max(n, c + 1);
                L = max(L, l + 1);
            }
        }
        const unsigned cost = (unsigned)(n * L) * (unsigned)((olens[k] + 127) >> 7);
        key[k] = (cost << 11) | (unsigned)k;
    }
    __syncthreads();

    for (int ksz = 2; ksz <= K_SZ; ksz <<= 1) {
        for (int j = ksz >> 1; j > 0; j >>= 1) {
            for (int i = tid; i < K_SZ; i += 1024) {
                const int ixj = i ^ j;
                if (ixj > i) {
                    const unsigned a = key[i], b = key[ixj];
                    const bool sw = ((i & ksz) == 0) ? (a < b) : (a > b); // descending
                    if (sw) { key[i] = b; key[ixj] = a; }
                }
            }
            __syncthreads();
        }
    }
    for (int i = tid; i < K_SZ; i += 1024)
        perm[i] = key[i] & 0x7FFu;
}

// ---------------------------------------------------------------------------
// Channel-pair dot2 (R11's proven inner loop): pe[i] = {xA[pos_i], xB[pos_i]},
// weight pair wp[l] = {wA[l], wB[l]} in LDS (broadcast at use). SALU-bumped
// uniform row pointers; all arrays 'unsigned' (spill discipline, R8-R13).
// Unit space is interleaved across SPL split-blocks for load balance.
template<int LC>
__device__ __forceinline__ void conv_all(
    const unsigned short* __restrict__ xT,
    const int*      __restrict__ sCh,          // 12 entries (zero-padded)
    const unsigned  (* __restrict__ sWp)[LMAX],// [NPAIR][LMAX] packed h2 pairs
    int npair, int d, int offr, int olen, float bias, int sp,
    int lane, int wid, float& psum, float& pmax)
{
    constexpr int NV = R + LC - 1;        // tap positions spanned by one item

    const int nj   = (olen + d - 1) / d;          // outputs per residue chain
    const int njb  = (nj + R - 1) / R;            // items per chain
    const int S    = (d >= 64) ? 1 : ((64 + d - 1) / d);
    const int len  = (njb + S - 1) / S;
    const int nunits = d * S;

    for (int u = sp * NW + wid; u < nunits; u += NW * SPL) {
        int q, seg;
        if (S == 1) { q = u; seg = 0; }
        else        { q = u % d; seg = u / d; }   // wave-uniform div
        const int jb0 = seg * len;
        const int jb1 = min(njb, jb0 + len);

        for (int jb = jb0; jb < jb1; ++jb) {
            const int tq = q + jb * (R * d);      // first output t of this item
            if (tq >= olen) break;
            const int tpos0 = tq + offr;          // real x coord of tap 0

            float y[R];
            #pragma unroll
            for (int r = 0; r < R; ++r) y[r] = bias;

            const bool fast = (tpos0 >= 0) && (tpos0 + (NV - 1) * d < T_SZ);

            if (fast) {
                for (int p = 0; p < npair; ++p) {
                    const int rbA = __builtin_amdgcn_readfirstlane(sCh[2*p  ] * T_SZ + tpos0);
                    const int rbB = __builtin_amdgcn_readfirstlane(sCh[2*p+1] * T_SZ + tpos0);
                    const unsigned short* rpA = xT + ((size_t)rbA << 6);  // uniform ptrs
                    const unsigned short* rpB = xT + ((size_t)rbB << 6);

                    unsigned vp[NV];
                    #pragma unroll
                    for (int i = 0; i < NV; ++i) {
                        const unsigned a = rpA[lane];                 // saddr + lane*2
                        const unsigned b = rpB[lane];
                        vp[i] = __builtin_amdgcn_perm(b, a, 0x05040100); // {a,b}
                        rpA += (d << 6); rpB += (d << 6);             // SALU bumps
                    }

                    const unsigned* wrow = &sWp[p][0];
                    #pragma unroll
                    for (int l = 0; l < LC; ++l) {
                        const unsigned w = wrow[l];                   // LDS broadcast
                        #pragma unroll
                        for (int r = 0; r < R; ++r)
                            y[r] = fdot2f(w, vp[l + r], y[r]);
                    }
                }
            } else {
                for (int p = 0; p < npair; ++p) {
                    const int rbA = __builtin_amdgcn_readfirstlane(sCh[2*p  ] * T_SZ);
                    const int rbB = __builtin_amdgcn_readfirstlane(sCh[2*p+1] * T_SZ);
                    const unsigned short* rowA = xT + ((size_t)rbA << 6);
                    const unsigned short* rowB = xT + ((size_t)rbB << 6);

                    unsigned vp[NV];
                    #pragma unroll
                    for (int i = 0; i < NV; ++i) {
                        const int tp  = tpos0 + i * d;                // wave-uniform
                        const int tpc = min(max(tp, 0), T_SZ - 1);
                        const unsigned a = rowA[((size_t)tpc << 6) + lane];
                        const unsigned b = rowB[((size_t)tpc << 6) + lane];
                        const unsigned pk = __builtin_amdgcn_perm(b, a, 0x05040100);
                        vp[i] = ((unsigned)tp < (unsigned)T_SZ) ? pk : 0u;
                    }

                    const unsigned* wrow = &sWp[p][0];
                    #pragma unroll
                    for (int l = 0; l < LC; ++l) {
                        const unsigned w = wrow[l];
                        #pragma unroll
                        for (int r = 0; r < R; ++r)
                            y[r] = fdot2f(w, vp[l + r], y[r]);
                    }
                }
            }

            #pragma unroll
            for (int r = 0; r < R; ++r) {
                const int t = tq + r * d;
                if (t < olen) {                   // wave-uniform branch
                    psum += 1.0f / (1.0f + __expf(3.0f - A_PARAM * y[r]));
                    pmax  = fmaxf(pmax, y[r]);
                }
            }
        }
    }
}

// NOTE: 2nd launch_bounds arg acts as min-blocks/CU on this toolchain
// ((512,8)->32 VGPR cap, (512,6)->40, (512,4)->48). (512,4) keeps full
// 32-wave/CU occupancy potential with adequate register budget.
__global__ __launch_bounds__(BLOCK_MAIN, 4) void rocket_tr(
    const unsigned short* __restrict__ xT,   // (C, T, 64) fp16 bits
    const unsigned* __restrict__ perm,       // heavy-first sorted k map
    const float* __restrict__ weights,       // (K, CMAX, LMAX)
    const float* __restrict__ biases,
    const int*   __restrict__ ch_idx,        // (K, CMAX)
    const int*   __restrict__ dils,
    const int*   __restrict__ offs,
    const int*   __restrict__ olens,
    float*       __restrict__ part)          // (K, SPL, 128) partials
{
    __shared__ float    sW[CMAX][LMAX];
    __shared__ unsigned sWp[NPAIR][LMAX];    // packed {W[2p][l], W[2p+1][l]}
    __shared__ int      sCh[2 * NPAIR];
    __shared__ int      sMeta[2];
    __shared__ float    sP[NW][64];
    __shared__ float    sM[NW][64];

    const int kidx = blockIdx.x / SPL;       // sorted position (heavy first)
    const int sp   = blockIdx.x % SPL;       // split index
    const int k    = (int)perm[kidx];
    const int tid  = threadIdx.x;

    if (tid < CMAX * LMAX)
        sW[tid / LMAX][tid % LMAX] = weights[(size_t)k * (CMAX * LMAX) + tid];
    if (tid < 2 * NPAIR)
        sCh[tid] = (tid < CMAX) ? ch_idx[(size_t)k * CMAX + tid] : 0;
    __syncthreads();

    if (tid < NPAIR * LMAX) {
        const int p = tid / LMAX;
        const int l = tid % LMAX;
        const float wA = sW[2 * p][l];
        const float wB = (2 * p + 1 < CMAX) ? sW[2 * p + 1][l] : 0.0f;
        h2 hh; hh.x = (_Float16)wA; hh.y = (_Float16)wB;
        sWp[p][l] = __builtin_bit_cast(unsigned, hh);
    }
    if (tid == 0) {
        // Effective channel/tap counts (zero-padded rows/taps contribute 0).
        int n = 0, L = 0;
        for (int c = 0; c < CMAX; ++c) {
            bool nz = false;
            for (int l = 0; l < LMAX; ++l) {
                if (sW[c][l] != 0.0f) { nz = true; if (l + 1 > L) L = l + 1; }
            }
            if (nz) n = c + 1;
        }
        sMeta[0] = n; sMeta[1] = L;
    }
    __syncthreads();

    const int   n     = sMeta[0];
    const int   L     = sMeta[1];
    const int   npair = (n + 1) >> 1;
    const int   d     = dils[k];
    const int   offr  = offs[k] - PL_PAD;  // real x coord offset (may be <0)
    const int   olen  = olens[k];
    const float bias  = biases[k];
    const int   lane  = tid & 63;
    const int   wid   = __builtin_amdgcn_readfirstlane(tid >> 6);

    // Bias contributes once per output; only split 0 seeds it so the
    // cross-split sum is correct. (Outputs are partitioned across splits by
    // unit, so bias must ride with whichever split computes the output —
    // it does: each output item is computed entirely by one split-block.)
    float psum = 0.0f;
    float pmax = -INFINITY;

    if (L <= 7)
        conv_all<7 >(xT, sCh, sWp, npair, d, offr, olen, bias, sp, lane, wid, psum, pmax);
    else if (L <= 9)
        conv_all<9 >(xT, sCh, sWp, npair, d, offr, olen, bias, sp, lane, wid, psum, pmax);
    else
        conv_all<11>(xT, sCh, sWp, npair, d, offr, olen, bias, sp, lane, wid, psum, pmax);

    sP[wid][lane] = psum;
    sM[wid][lane] = pmax;
    __syncthreads();

    if (tid < 64) {
        float s = 0.0f, m = -INFINITY;
        #pragma unroll
        for (int w = 0; w < NW; ++w) {
            s += sP[w][tid];
            m  = fmaxf(m, sM[w][tid]);
        }
        float* pp = part + ((size_t)k * SPL + sp) * 128;
        pp[tid]      = s;     // partial sigmoid-sum for batch tid
        pp[64 + tid] = m;     // partial max for batch tid
    }
}

// ---------------------------------------------------------------------------
// Deterministic combine: out[b][2k] = (sum_sp psum)/olen, out[b][2k+1] = max.
__global__ __launch_bounds__(256) void combine_kernel(
    const float* __restrict__ part,          // (K, SPL, 128)
    const int*   __restrict__ olens,
    float*       __restrict__ out)           // (B, 2K)
{
    const int idx = blockIdx.x * 256 + threadIdx.x;   // [0, K*64)
    if (idx >= K_SZ * 64) return;
    const int k = idx >> 6;
    const int b = idx & 63;
    const float* pp = part + (size_t)k * SPL * 128;
    float s = 0.0f, m = -INFINITY;
    #pragma unroll
    for (int sp = 0; sp < SPL; ++sp) {
        s += pp[sp * 128 + b];
        m  = fmaxf(m, pp[sp * 128 + 64 + b]);
    }
    out[(size_t)b * (2 * K_SZ) + 2 * k]     = s / (float)olens[k];
    out[(size_t)b * (2 * K_SZ) + 2 * k + 1] = m;
}

// ---------------------------------------------------------------------------
// Fallback (ws too small): simple checked-gather kernel, known correct.
__global__ __launch_bounds__(256) void rocket_fallback(
    const float* __restrict__ x,
    const float* __restrict__ weights,
    const float* __restrict__ biases,
    const int*   __restrict__ ch_idx,
    const int*   __restrict__ dils,
    const int*   __restrict__ offs,
    const int*   __restrict__ olens,
    float*       __restrict__ out)
{
    __shared__ float sW[CMAX][LMAX];
    __shared__ int   sCh[CMAX];
    __shared__ float sRed[2][4];

    const int k   = blockIdx.x;
    const int tid = threadIdx.x;

    if (tid < CMAX * LMAX)
        sW[tid / LMAX][tid % LMAX] = weights[(size_t)k * (CMAX * LMAX) + tid];
    if (tid < CMAX)
        sCh[tid] = ch_idx[(size_t)k * CMAX + tid];
    __syncthreads();

    const int   d    = dils[k];
    const int   off  = offs[k] - PL_PAD;
    const int   olen = olens[k];
    const float bias = biases[k];
    const int   lane = tid & 63;
    const int   wid  = tid >> 6;

    for (int b = blockIdx.y; b < B_SZ; b += gridDim.y) {
        float psum = 0.0f, pmax = -INFINITY;
        for (int t = tid; t < T_SZ; t += 256) {
            float y = bias;
            for (int c = 0; c < CMAX; ++c) {
                const float* xb = x + ((size_t)b * C_SZ + sCh[c]) * T_SZ;
                int pos = off + t;
                for (int l = 0; l < LMAX; ++l) {
                    const float xv = ((unsigned)pos < (unsigned)T_SZ) ? xb[pos] : 0.0f;
                    y = fmaf(sW[c][l], xv, y);
                    pos += d;
                }
            }
            if (t < olen) {
                psum += 1.0f / (1.0f + __expf(3.0f - A_PARAM * y));
                pmax = fmaxf(pmax, y);
            }
        }
        for (int o = 32; o > 0; o >>= 1) {
            psum += __shfl_down(psum, o, 64);
            pmax  = fmaxf(pmax, __shfl_down(pmax, o, 64));
        }
        if (lane == 0) { sRed[0][wid] = psum; sRed[1][wid] = pmax; }
        __syncthreads();
        if (tid == 0) {
            const float s = sRed[0][0] + sRed[0][1] + sRed[0][2] + sRed[0][3];
            const float m = fmaxf(fmaxf(sRed[1][0], sRed[1][1]),
                                  fmaxf(sRed[1][2], sRed[1][3]));
            out[(size_t)b * (2 * K_SZ) + 2 * k]     = s / (float)olen;
            out[(size_t)b * (2 * K_SZ) + 2 * k + 1] = m;
        }
        __syncthreads();
    }
}

// ---------------------------------------------------------------------------
extern "C" void kernel_launch(void* const* d_in, const int* in_sizes, int n_in,
                              void* d_out, int out_size, void* d_ws, size_t ws_size,
                              hipStream_t stream) {
    const float* x       = (const float*)d_in[0];
    const float* weights = (const float*)d_in[1];
    const float* biases  = (const float*)d_in[2];
    const int*   ch_idx  = (const int*)  d_in[3];
    const int*   dils    = (const int*)  d_in[4];
    const int*   offs    = (const int*)  d_in[5];
    const int*   olens   = (const int*)  d_in[6];
    float*       out     = (float*)d_out;

    const size_t xt_bytes   = (size_t)C_SZ * T_SZ * 64 * sizeof(unsigned short); // 3.15 MB
    const size_t perm_bytes = K_SZ * sizeof(unsigned);
    const size_t part_bytes = (size_t)K_SZ * SPL * 128 * sizeof(float);          // 4.19 MB
    const size_t need       = xt_bytes + perm_bytes + part_bytes;

    if (ws_size >= need) {
        unsigned short* xT = (unsigned short*)d_ws;
        unsigned* perm     = (unsigned*)((char*)d_ws + xt_bytes);
        float*    part     = (float*)((char*)d_ws + xt_bytes + perm_bytes);
        dim3 tgrid(C_SZ, T_SZ / 128);
        trh_kernel<<<tgrid, 256, 0, stream>>>(x, xT);
        sched_kernel<<<1, 1024, 0, stream>>>(weights, olens, perm);
        rocket_tr<<<K_SZ * SPL, BLOCK_MAIN, 0, stream>>>(xT, perm, weights,
                                                         biases, ch_idx, dils,
                                                         offs, olens, part);
        combine_kernel<<<(K_SZ * 64 + 255) / 256, 256, 0, stream>>>(part, olens, out);
    } else {
        dim3 grid(K_SZ, 16);
        rocket_fallback<<<grid, 256, 0, stream>>>(x, weights, biases, ch_idx,
                                                  dils, offs, olens, out);
    }
}

// Round 18
// 629.893 us; speedup vs baseline: 1.8313x; 1.0764x over previous
//
#include <hip/hip_runtime.h>
#include <math.h>

// Problem constants (fixed by the reference setup)
#define B_SZ   64
#define C_SZ   12
#define T_SZ   2048
#define K_SZ   2048
#define LMAX   11
#define CMAX   11     // C-1
#define NPAIR  6      // channel pairs: ceil(12/2), padded with zero-weight
#define PL_PAD 1024
#define A_PARAM 7.0f

#define NW     8      // waves per block in main kernel
#define BLOCK_MAIN (NW * 64)
#define R      8      // outputs per thread item (dilation-strided register tile)
#define SPL    4      // chain-splits per kernel (8192 work items)
#define NBLK   1024   // persistent blocks: 4/CU x 256 CU

typedef _Float16 h2 __attribute__((ext_vector_type(2)));

// Pure register bitcast — NO union (unions defeat SROA -> scratch arrays).
__device__ __forceinline__ float fdot2f(unsigned w, unsigned v, float acc) {
    return __builtin_amdgcn_fdot2(__builtin_bit_cast(h2, w),
                                  __builtin_bit_cast(h2, v), acc, false);
}

// ---------------------------------------------------------------------------
// Transpose to fp16: xT[c][t][b] = fp16(x[b][c][t]). 3.15 MB -> per-XCD L2.
__global__ __launch_bounds__(256) void trh_kernel(const float* __restrict__ x,
                                                  unsigned short* __restrict__ xT) {
    const int c    = blockIdx.x;
    const int lane = threadIdx.x & 63;
    const int wid  = threadIdx.x >> 6;
    const int t0   = blockIdx.y * 128 + wid * 32;
    const float* xrow = x + ((size_t)lane * C_SZ + c) * T_SZ + t0;
    unsigned short* dst = xT + ((size_t)c * T_SZ + t0) * 64 + lane;
    #pragma unroll 8
    for (int i = 0; i < 32; ++i) {
        const _Float16 h = (_Float16)xrow[i];
        dst[i * 64] = __builtin_bit_cast(unsigned short, h);
    }
}

// ---------------------------------------------------------------------------
// Schedule: cost[k] ~ n*L*ceil(olen/128); bitonic sort descending (heavy
// first). Also: meta[k] = n | (L<<8), and zero the work-queue counter.
__global__ __launch_bounds__(1024) void sched_kernel(const float* __restrict__ w,
                                                     const int* __restrict__ olens,
                                                     unsigned* __restrict__ perm,
                                                     unsigned* __restrict__ meta,
                                                     unsigned* __restrict__ counter) {
    __shared__ unsigned key[K_SZ];
    const int tid = threadIdx.x;
    if (tid == 0) *counter = 0u;

    for (int k = tid; k < K_SZ; k += 1024) {
        const float* wk = w + (size_t)k * (CMAX * LMAX);
        int n = 0, L = 0;
        for (int e = 0; e < CMAX * LMAX; ++e) {
            if (wk[e] != 0.0f) {
                const int c = e / LMAX, l = e % LMAX;
                n = max(n, c + 1);
                L = max(L, l + 1);
            }
        }
        meta[k] = (unsigned)n | ((unsigned)L << 8);
        const unsigned cost = (unsigned)(n * L) * (unsigned)((olens[k] + 127) >> 7);
        key[k] = (cost << 11) | (unsigned)k;
    }
    __syncthreads();

    for (int ksz = 2; ksz <= K_SZ; ksz <<= 1) {
        for (int j = ksz >> 1; j > 0; j >>= 1) {
            for (int i = tid; i < K_SZ; i += 1024) {
                const int ixj = i ^ j;
                if (ixj > i) {
                    const unsigned a = key[i], b = key[ixj];
                    const bool sw = ((i & ksz) == 0) ? (a < b) : (a > b); // descending
                    if (sw) { key[i] = b; key[ixj] = a; }
                }
            }
            __syncthreads();
        }
    }
    for (int i = tid; i < K_SZ; i += 1024)
        perm[i] = key[i] & 0x7FFu;
}

// ---------------------------------------------------------------------------
// R17's proven inner loop (channel-pair dot2, SALU-bumped uniform pointers,
// all-'unsigned' arrays). Unit space interleaved across SPL splits.
template<int LC>
__device__ __forceinline__ void conv_all(
    const unsigned short* __restrict__ xT,
    const int*      __restrict__ sCh,          // 12 entries (zero-padded)
    const unsigned  (* __restrict__ sWp)[LMAX],// [NPAIR][LMAX] packed h2 pairs
    int npair, int d, int offr, int olen, float bias, int sp,
    int lane, int wid, float& psum, float& pmax)
{
    constexpr int NV = R + LC - 1;        // tap positions spanned by one item

    const int nj   = (olen + d - 1) / d;          // outputs per residue chain
    const int njb  = (nj + R - 1) / R;            // items per chain
    const int S    = (d >= 64) ? 1 : ((64 + d - 1) / d);
    const int len  = (njb + S - 1) / S;
    const int nunits = d * S;

    for (int u = sp * NW + wid; u < nunits; u += NW * SPL) {
        int q, seg;
        if (S == 1) { q = u; seg = 0; }
        else        { q = u % d; seg = u / d; }   // wave-uniform div
        const int jb0 = seg * len;
        const int jb1 = min(njb, jb0 + len);

        for (int jb = jb0; jb < jb1; ++jb) {
            const int tq = q + jb * (R * d);      // first output t of this item
            if (tq >= olen) break;
            const int tpos0 = tq + offr;          // real x coord of tap 0

            float y[R];
            #pragma unroll
            for (int r = 0; r < R; ++r) y[r] = bias;

            const bool fast = (tpos0 >= 0) && (tpos0 + (NV - 1) * d < T_SZ);

            if (fast) {
                for (int p = 0; p < npair; ++p) {
                    const int rbA = __builtin_amdgcn_readfirstlane(sCh[2*p  ] * T_SZ + tpos0);
                    const int rbB = __builtin_amdgcn_readfirstlane(sCh[2*p+1] * T_SZ + tpos0);
                    const unsigned short* rpA = xT + ((size_t)rbA << 6);  // uniform ptrs
                    const unsigned short* rpB = xT + ((size_t)rbB << 6);

                    unsigned vp[NV];
                    #pragma unroll
                    for (int i = 0; i < NV; ++i) {
                        const unsigned a = rpA[lane];                 // saddr + lane*2
                        const unsigned b = rpB[lane];
                        vp[i] = __builtin_amdgcn_perm(b, a, 0x05040100); // {a,b}
                        rpA += (d << 6); rpB += (d << 6);             // SALU bumps
                    }

                    const unsigned* wrow = &sWp[p][0];
                    #pragma unroll
                    for (int l = 0; l < LC; ++l) {
                        const unsigned w = wrow[l];                   // LDS broadcast
                        #pragma unroll
                        for (int r = 0; r < R; ++r)
                            y[r] = fdot2f(w, vp[l + r], y[r]);
                    }
                }
            } else {
                for (int p = 0; p < npair; ++p) {
                    const int rbA = __builtin_amdgcn_readfirstlane(sCh[2*p  ] * T_SZ);
                    const int rbB = __builtin_amdgcn_readfirstlane(sCh[2*p+1] * T_SZ);
                    const unsigned short* rowA = xT + ((size_t)rbA << 6);
                    const unsigned short* rowB = xT + ((size_t)rbB << 6);

                    unsigned vp[NV];
                    #pragma unroll
                    for (int i = 0; i < NV; ++i) {
                        const int tp  = tpos0 + i * d;                // wave-uniform
                        const int tpc = min(max(tp, 0), T_SZ - 1);
                        const unsigned a = rowA[((size_t)tpc << 6) + lane];
                        const unsigned b = rowB[((size_t)tpc << 6) + lane];
                        const unsigned pk = __builtin_amdgcn_perm(b, a, 0x05040100);
                        vp[i] = ((unsigned)tp < (unsigned)T_SZ) ? pk : 0u;
                    }

                    const unsigned* wrow = &sWp[p][0];
                    #pragma unroll
                    for (int l = 0; l < LC; ++l) {
                        const unsigned w = wrow[l];
                        #pragma unroll
                        for (int r = 0; r < R; ++r)
                            y[r] = fdot2f(w, vp[l + r], y[r]);
                    }
                }
            }

            #pragma unroll
            for (int r = 0; r < R; ++r) {
                const int t = tq + r * d;
                if (t < olen) {                   // wave-uniform branch
                    psum += 1.0f / (1.0f + __expf(3.0f - A_PARAM * y[r]));
                    pmax  = fmaxf(pmax, y[r]);
                }
            }
        }
    }
}

// ---------------------------------------------------------------------------
// Persistent work-queue main kernel: NBLK resident blocks pop (kidx, sp)
// items heavy-first from an atomic counter. Each item writes its own partial
// slot -> deterministic regardless of which block executes it.
__global__ __launch_bounds__(BLOCK_MAIN, 4) void rocket_tr(
    const unsigned short* __restrict__ xT,   // (C, T, 64) fp16 bits
    const unsigned* __restrict__ perm,       // heavy-first sorted k map
    const unsigned* __restrict__ meta,       // n | (L<<8) per k
    const float* __restrict__ weights,       // (K, CMAX, LMAX)
    const float* __restrict__ biases,
    const int*   __restrict__ ch_idx,        // (K, CMAX)
    const int*   __restrict__ dils,
    const int*   __restrict__ offs,
    const int*   __restrict__ olens,
    float*       __restrict__ part,          // (K, SPL, 128) partials
    unsigned*    __restrict__ counter)
{
    __shared__ unsigned sWp[NPAIR][LMAX];    // packed {W[2p][l], W[2p+1][l]}
    __shared__ int      sCh[2 * NPAIR];
    __shared__ int      sItem;
    __shared__ float    sP[NW][64];
    __shared__ float    sM[NW][64];

    const int tid  = threadIdx.x;
    const int lane = tid & 63;
    const int wid  = __builtin_amdgcn_readfirstlane(tid >> 6);

    for (;;) {
        __syncthreads();                      // protect sItem/sWp/sCh/sP reuse
        if (tid == 0) sItem = (int)atomicAdd(counter, 1u);
        __syncthreads();
        const int item = sItem;
        if (item >= K_SZ * SPL) break;        // uniform exit

        const int kidx = item / SPL;          // sorted position (heavy first)
        const int sp   = item % SPL;
        const int k    = (int)perm[kidx];

        // Pack weights straight from global (66 threads), channels (12).
        if (tid < NPAIR * LMAX) {
            const int p = tid / LMAX;
            const int l = tid % LMAX;
            const float wA = weights[(size_t)k * (CMAX * LMAX) + (2 * p) * LMAX + l];
            const float wB = (2 * p + 1 < CMAX)
                ? weights[(size_t)k * (CMAX * LMAX) + (2 * p + 1) * LMAX + l] : 0.0f;
            h2 hh; hh.x = (_Float16)wA; hh.y = (_Float16)wB;
            sWp[p][l] = __builtin_bit_cast(unsigned, hh);
        }
        if (tid >= 64 && tid < 64 + 2 * NPAIR) {
            const int c = tid - 64;
            sCh[c] = (c < CMAX) ? ch_idx[(size_t)k * CMAX + c] : 0;
        }
        __syncthreads();

        const unsigned mk = meta[k];
        const int   n     = (int)(mk & 0xFFu);
        const int   L     = (int)((mk >> 8) & 0xFFu);
        const int   npair = (n + 1) >> 1;
        const int   d     = dils[k];
        const int   offr  = offs[k] - PL_PAD;
        const int   olen  = olens[k];
        const float bias  = biases[k];

        float psum = 0.0f;
        float pmax = -INFINITY;

        if (L <= 7)
            conv_all<7 >(xT, sCh, sWp, npair, d, offr, olen, bias, sp, lane, wid, psum, pmax);
        else if (L <= 9)
            conv_all<9 >(xT, sCh, sWp, npair, d, offr, olen, bias, sp, lane, wid, psum, pmax);
        else
            conv_all<11>(xT, sCh, sWp, npair, d, offr, olen, bias, sp, lane, wid, psum, pmax);

        sP[wid][lane] = psum;
        sM[wid][lane] = pmax;
        __syncthreads();

        if (tid < 64) {
            float s = 0.0f, m = -INFINITY;
            #pragma unroll
            for (int w = 0; w < NW; ++w) {
                s += sP[w][tid];
                m  = fmaxf(m, sM[w][tid]);
            }
            float* pp = part + ((size_t)k * SPL + sp) * 128;
            pp[tid]      = s;     // partial sigmoid-sum for batch tid
            pp[64 + tid] = m;     // partial max for batch tid
        }
    }
}

// ---------------------------------------------------------------------------
// Deterministic combine: out[b][2k] = (sum_sp psum)/olen, out[b][2k+1] = max.
__global__ __launch_bounds__(256) void combine_kernel(
    const float* __restrict__ part,          // (K, SPL, 128)
    const int*   __restrict__ olens,
    float*       __restrict__ out)           // (B, 2K)
{
    const int idx = blockIdx.x * 256 + threadIdx.x;   // [0, K*64)
    if (idx >= K_SZ * 64) return;
    const int k = idx >> 6;
    const int b = idx & 63;
    const float* pp = part + (size_t)k * SPL * 128;
    float s = 0.0f, m = -INFINITY;
    #pragma unroll
    for (int sp = 0; sp < SPL; ++sp) {
        s += pp[sp * 128 + b];
        m  = fmaxf(m, pp[sp * 128 + 64 + b]);
    }
    out[(size_t)b * (2 * K_SZ) + 2 * k]     = s / (float)olens[k];
    out[(size_t)b * (2 * K_SZ) + 2 * k + 1] = m;
}

// ---------------------------------------------------------------------------
// Fallback (ws too small): simple checked-gather kernel, known correct.
__global__ __launch_bounds__(256) void rocket_fallback(
    const float* __restrict__ x,
    const float* __restrict__ weights,
    const float* __restrict__ biases,
    const int*   __restrict__ ch_idx,
    const int*   __restrict__ dils,
    const int*   __restrict__ offs,
    const int*   __restrict__ olens,
    float*       __restrict__ out)
{
    __shared__ float sW[CMAX][LMAX];
    __shared__ int   sCh[CMAX];
    __shared__ float sRed[2][4];

    const int k   = blockIdx.x;
    const int tid = threadIdx.x;

    if (tid < CMAX * LMAX)
        sW[tid / LMAX][tid % LMAX] = weights[(size_t)k * (CMAX * LMAX) + tid];
    if (tid < CMAX)
        sCh[tid] = ch_idx[(size_t)k * CMAX + tid];
    __syncthreads();

    const int   d    = dils[k];
    const int   off  = offs[k] - PL_PAD;
    const int   olen = olens[k];
    const float bias = biases[k];
    const int   lane = tid & 63;
    const int   wid  = tid >> 6;

    for (int b = blockIdx.y; b < B_SZ; b += gridDim.y) {
        float psum = 0.0f, pmax = -INFINITY;
        for (int t = tid; t < T_SZ; t += 256) {
            float y = bias;
            for (int c = 0; c < CMAX; ++c) {
                const float* xb = x + ((size_t)b * C_SZ + sCh[c]) * T_SZ;
                int pos = off + t;
                for (int l = 0; l < LMAX; ++l) {
                    const float xv = ((unsigned)pos < (unsigned)T_SZ) ? xb[pos] : 0.0f;
                    y = fmaf(sW[c][l], xv, y);
                    pos += d;
                }
            }
            if (t < olen) {
                psum += 1.0f / (1.0f + __expf(3.0f - A_PARAM * y));
                pmax = fmaxf(pmax, y);
            }
        }
        for (int o = 32; o > 0; o >>= 1) {
            psum += __shfl_down(psum, o, 64);
            pmax  = fmaxf(pmax, __shfl_down(pmax, o, 64));
        }
        if (lane == 0) { sRed[0][wid] = psum; sRed[1][wid] = pmax; }
        __syncthreads();
        if (tid == 0) {
            const float s = sRed[0][0] + sRed[0][1] + sRed[0][2] + sRed[0][3];
            const float m = fmaxf(fmaxf(sRed[1][0], sRed[1][1]),
                                  fmaxf(sRed[1][2], sRed[1][3]));
            out[(size_t)b * (2 * K_SZ) + 2 * k]     = s / (float)olen;
            out[(size_t)b * (2 * K_SZ) + 2 * k + 1] = m;
        }
        __syncthreads();
    }
}

// ---------------------------------------------------------------------------
extern "C" void kernel_launch(void* const* d_in, const int* in_sizes, int n_in,
                              void* d_out, int out_size, void* d_ws, size_t ws_size,
                              hipStream_t stream) {
    const float* x       = (const float*)d_in[0];
    const float* weights = (const float*)d_in[1];
    const float* biases  = (const float*)d_in[2];
    const int*   ch_idx  = (const int*)  d_in[3];
    const int*   dils    = (const int*)  d_in[4];
    const int*   offs    = (const int*)  d_in[5];
    const int*   olens   = (const int*)  d_in[6];
    float*       out     = (float*)d_out;

    const size_t xt_bytes   = (size_t)C_SZ * T_SZ * 64 * sizeof(unsigned short); // 3.15 MB
    const size_t perm_bytes = K_SZ * sizeof(unsigned);
    const size_t meta_bytes = K_SZ * sizeof(unsigned);
    const size_t part_bytes = (size_t)K_SZ * SPL * 128 * sizeof(float);          // 4.19 MB
    const size_t need       = xt_bytes + perm_bytes + meta_bytes + part_bytes + 128;

    if (ws_size >= need) {
        char* wsb = (char*)d_ws;
        unsigned short* xT   = (unsigned short*)wsb;
        unsigned* perm       = (unsigned*)(wsb + xt_bytes);
        unsigned* meta       = (unsigned*)(wsb + xt_bytes + perm_bytes);
        float*    part       = (float*)(wsb + xt_bytes + perm_bytes + meta_bytes);
        unsigned* counter    = (unsigned*)(wsb + xt_bytes + perm_bytes + meta_bytes + part_bytes);

        dim3 tgrid(C_SZ, T_SZ / 128);
        trh_kernel<<<tgrid, 256, 0, stream>>>(x, xT);
        sched_kernel<<<1, 1024, 0, stream>>>(weights, olens, perm, meta, counter);
        rocket_tr<<<NBLK, BLOCK_MAIN, 0, stream>>>(xT, perm, meta, weights,
                                                   biases, ch_idx, dils, offs,
                                                   olens, part, counter);
        combine_kernel<<<(K_SZ * 64 + 255) / 256, 256, 0, stream>>>(part, olens, out);
    } else {
        dim3 grid(K_SZ, 16);
        rocket_fallback<<<grid, 256, 0, stream>>>(x, weights, biases, ch_idx,
                                                  dils, offs, olens, out);
    }
}